// Round 1
// baseline (26.965 us; speedup 1.0000x reference)
//
#include <hip/hip_runtime.h>

// MaxPool3d fused: x[8,64,256,256] f32, kernel=stride=(2,2,2), pad 0
// -> out[8,32,128,128] f32.
// Each thread: 4x float4 loads (2 rows x 2 depths), elementwise max,
// horizontal pair-max -> float2 store (2 outputs).

#define B   8
#define D   64
#define H   256
#define W   256
#define OD  (D / 2)
#define OH  (H / 2)
#define OW  (W / 2)

__global__ __launch_bounds__(256) void maxpool3d_kernel(
    const float* __restrict__ x, float* __restrict__ out) {
    // total float2 outputs: B*OD*OH*(OW/2) = 2,097,152
    unsigned tid = blockIdx.x * 256u + threadIdx.x;

    unsigned ow2 = tid & 63u;          // OW/2 = 64 float2 per output row
    unsigned t   = tid >> 6;
    unsigned oh  = t & 127u;           // OH = 128
    t >>= 7;
    unsigned od  = t & 31u;            // OD = 32
    unsigned b   = t >> 5;

    // input base: [b][od*2][oh*2][ow2*4]
    const size_t plane = (size_t)H * W;            // 65536
    const size_t ibase = (((size_t)b * D + od * 2u) * H + oh * 2u) * W + ow2 * 4u;

    const float4* p00 = (const float4*)(x + ibase);                 // d, h
    const float4* p01 = (const float4*)(x + ibase + W);             // d, h+1
    const float4* p10 = (const float4*)(x + ibase + plane);         // d+1, h
    const float4* p11 = (const float4*)(x + ibase + plane + W);     // d+1, h+1

    float4 a = *p00;
    float4 c = *p01;
    float4 e = *p10;
    float4 g = *p11;

    float4 m;
    m.x = fmaxf(fmaxf(a.x, c.x), fmaxf(e.x, g.x));
    m.y = fmaxf(fmaxf(a.y, c.y), fmaxf(e.y, g.y));
    m.z = fmaxf(fmaxf(a.z, c.z), fmaxf(e.z, g.z));
    m.w = fmaxf(fmaxf(a.w, c.w), fmaxf(e.w, g.w));

    float2 r;
    r.x = fmaxf(m.x, m.y);
    r.y = fmaxf(m.z, m.w);

    // output index: [b][od][oh][ow2*2]
    const size_t obase = (((size_t)b * OD + od) * OH + oh) * OW + ow2 * 2u;
    *(float2*)(out + obase) = r;
}

extern "C" void kernel_launch(void* const* d_in, const int* in_sizes, int n_in,
                              void* d_out, int out_size, void* d_ws, size_t ws_size,
                              hipStream_t stream) {
    const float* x = (const float*)d_in[0];
    float* out = (float*)d_out;

    const unsigned total_f2 = B * OD * OH * (OW / 2);  // 2,097,152
    const unsigned blocks = total_f2 / 256u;            // 8192
    maxpool3d_kernel<<<blocks, 256, 0, stream>>>(x, out);
}